// Round 3
// baseline (1894.935 us; speedup 1.0000x reference)
//
#include <hip/hip_runtime.h>
#include <hip/hip_bf16.h>

// ---------------------------------------------------------------------------
// Fused MoE-gate network, fp32 baseline (3rd submit — rounds 1-2 never ran:
// broker GPUAcquisitionTimeout both times; identical kernel, audited).
//   k_fuse: e = relu(cat(s_e,p_e) @ W_fuse + b_fuse)          -> ws (fp32)
//   k_gate: g = tanh(e @ W_a + b_a) ; logits in-register ;
//           softmax / sigmoid / argmax / out epilogue fused.
// Design notes:
//  - per-thread 8x16 micro-tile, cols = 64*j + 4*cg (+m): consecutive lanes
//    read consecutive 16B from LDS -> conflict-free b128 W reads.
//  - X staged transposed [KC][BM+4]: compute reads are wave-uniform-row
//    (broadcast); staging writes 2-way max (free per m136).
//  - top-1 gate == one-hot 1.0 -> out = dot(e[row, 32a:32a+32], W_out[32a:]).
// ---------------------------------------------------------------------------

#define H   256
#define EXP 8
#define KC  32
#define BM  128
#define NT  256

__device__ __forceinline__ float4 fma4(float a, float4 b, float4 c) {
  c.x = fmaf(a, b.x, c.x);
  c.y = fmaf(a, b.y, c.y);
  c.z = fmaf(a, b.z, c.z);
  c.w = fmaf(a, b.w, c.w);
  return c;
}

__device__ __forceinline__ float fast_tanh(float x) {
  // tanh(x) = 1 - 2/(e^{2x}+1); abs err ~1e-6, graceful at +-inf.
  const float u = __expf(2.0f * x);
  return 1.0f - 2.0f / (u + 1.0f);
}

__device__ __forceinline__ float sigm(float x) {
  return 1.0f / (1.0f + __expf(-x));
}

__device__ __forceinline__ float redx16(float v) {
  v += __shfl_xor(v, 1);
  v += __shfl_xor(v, 2);
  v += __shfl_xor(v, 4);
  v += __shfl_xor(v, 8);
  return v;
}
__device__ __forceinline__ float4 red4(float4 v) {
  v.x = redx16(v.x); v.y = redx16(v.y); v.z = redx16(v.z); v.w = redx16(v.w);
  return v;
}

#define ROW_FMA(XI, I)                      \
  acc[I][0] = fma4(XI, w0, acc[I][0]);      \
  acc[I][1] = fma4(XI, w1, acc[I][1]);      \
  acc[I][2] = fma4(XI, w2, acc[I][2]);      \
  acc[I][3] = fma4(XI, w3, acc[I][3]);

// ---------------------------------------------------------------------------
__global__ __launch_bounds__(NT, 2) void k_fuse(
    const float* __restrict__ s_e, const float* __restrict__ p_e,
    const float* __restrict__ W_fuse, const float* __restrict__ b_fuse,
    float* __restrict__ e_out)
{
  __shared__ float Xl[KC][BM + 4];
  __shared__ float Wl[KC][H];
  const int tid = threadIdx.x;
  const int cg  = tid & 15;        // col group: cols 64*j + 4*cg + m
  const int rg  = tid >> 4;        // row group: rows rg*8 + i
  const long row0 = (long)blockIdx.x * BM;
  const int lr = tid >> 1;         // staging: row 0..127
  const int lh = tid & 1;          // staging: k half (16 floats)

  float4 acc[8][4];
#pragma unroll
  for (int i = 0; i < 8; ++i)
#pragma unroll
    for (int j = 0; j < 4; ++j) acc[i][j] = make_float4(0.f, 0.f, 0.f, 0.f);

  float4 xs[4], ws[8];

  auto load_chunk = [&](int c) {
    const int k0 = c * KC;
    const float* xbase = (k0 < H) ? (s_e + (row0 + lr) * H + k0 + lh * 16)
                                  : (p_e + (row0 + lr) * H + (k0 - H) + lh * 16);
    const float4* xp = (const float4*)xbase;
#pragma unroll
    for (int q = 0; q < 4; ++q) xs[q] = xp[q];
    const float4* wp = (const float4*)(W_fuse + (long)k0 * H);
#pragma unroll
    for (int s = 0; s < 8; ++s) ws[s] = wp[tid + NT * s];
  };

  auto store_chunk = [&]() {
#pragma unroll
    for (int q = 0; q < 4; ++q) {
      const int kb = lh * 16 + q * 4;
      Xl[kb + 0][lr] = xs[q].x;
      Xl[kb + 1][lr] = xs[q].y;
      Xl[kb + 2][lr] = xs[q].z;
      Xl[kb + 3][lr] = xs[q].w;
    }
    float4* wl4 = (float4*)&Wl[0][0];
#pragma unroll
    for (int s = 0; s < 8; ++s) wl4[tid + NT * s] = ws[s];
  };

  auto compute = [&]() {
#pragma unroll 8
    for (int kk = 0; kk < KC; ++kk) {
      const float4 xa = *(const float4*)&Xl[kk][rg * 8];
      const float4 xb = *(const float4*)&Xl[kk][rg * 8 + 4];
      const float4 w0 = *(const float4*)&Wl[kk][4 * cg];
      const float4 w1 = *(const float4*)&Wl[kk][4 * cg + 64];
      const float4 w2 = *(const float4*)&Wl[kk][4 * cg + 128];
      const float4 w3 = *(const float4*)&Wl[kk][4 * cg + 192];
      ROW_FMA(xa.x, 0) ROW_FMA(xa.y, 1) ROW_FMA(xa.z, 2) ROW_FMA(xa.w, 3)
      ROW_FMA(xb.x, 4) ROW_FMA(xb.y, 5) ROW_FMA(xb.z, 6) ROW_FMA(xb.w, 7)
    }
  };

  const int NC = (2 * H) / KC;   // 16
  load_chunk(0);
  for (int c = 0; c < NC; ++c) {
    __syncthreads();
    store_chunk();
    __syncthreads();
    if (c + 1 < NC) load_chunk(c + 1);
    compute();
  }

#pragma unroll
  for (int j = 0; j < 4; ++j) {
    const int col = 64 * j + 4 * cg;
    const float4 bf = *(const float4*)&b_fuse[col];
#pragma unroll
    for (int i = 0; i < 8; ++i) {
      float4 v = acc[i][j];
      v.x = fmaxf(v.x + bf.x, 0.f);
      v.y = fmaxf(v.y + bf.y, 0.f);
      v.z = fmaxf(v.z + bf.z, 0.f);
      v.w = fmaxf(v.w + bf.w, 0.f);
      *(float4*)&e_out[(row0 + rg * 8 + i) * H + col] = v;
    }
  }
}

// ---------------------------------------------------------------------------
#define PL_ACCUM(MM, COMP)                                             \
  {                                                                    \
    const int col = 64 * j + 4 * cg + MM;                              \
    const float4 wx0 = *(const float4*)(W_smax  + col * EXP);          \
    const float4 wx1 = *(const float4*)(W_smax  + col * EXP + 4);      \
    const float4 wg0 = *(const float4*)(W_smoid + col * EXP);          \
    const float4 wg1 = *(const float4*)(W_smoid + col * EXP + 4);      \
    _Pragma("unroll")                                                  \
    for (int i = 0; i < 4; ++i) {                                      \
      const float g = acc[hh * 4 + i][j].COMP;                         \
      pl[i][0] = fma4(g, wx0, pl[i][0]);                               \
      pl[i][1] = fma4(g, wx1, pl[i][1]);                               \
      pl[i][2] = fma4(g, wg0, pl[i][2]);                               \
      pl[i][3] = fma4(g, wg1, pl[i][3]);                               \
    }                                                                  \
  }

__global__ __launch_bounds__(NT, 2) void k_gate(
    const float* __restrict__ e_in,
    const float* __restrict__ W_a,    const float* __restrict__ b_a,
    const float* __restrict__ W_smax, const float* __restrict__ b_smax,
    const float* __restrict__ W_smoid,const float* __restrict__ b_smoid,
    const float* __restrict__ W_out,  const float* __restrict__ b_out,
    float* __restrict__ out0, float* __restrict__ out_sm,
    float* __restrict__ out_sg)
{
  __shared__ float Xl[KC][BM + 4];
  __shared__ float Wl[KC][H];
  const int tid = threadIdx.x;
  const int cg  = tid & 15;
  const int rg  = tid >> 4;
  const long row0 = (long)blockIdx.x * BM;
  const int lr = tid >> 1;
  const int lh = tid & 1;

  const float4 bsx0 = *(const float4*)&b_smax[0];
  const float4 bsx1 = *(const float4*)&b_smax[4];
  const float4 bsg0 = *(const float4*)&b_smoid[0];
  const float4 bsg1 = *(const float4*)&b_smoid[4];
  const float  b_out0 = b_out[0];

  float4 acc[8][4];
#pragma unroll
  for (int i = 0; i < 8; ++i)
#pragma unroll
    for (int j = 0; j < 4; ++j) acc[i][j] = make_float4(0.f, 0.f, 0.f, 0.f);

  float4 xs[4], ws[8];

  auto load_chunk = [&](int c) {
    const int k0 = c * KC;
    const float4* xp = (const float4*)(e_in + (row0 + lr) * H + k0 + lh * 16);
#pragma unroll
    for (int q = 0; q < 4; ++q) xs[q] = xp[q];
    const float4* wp = (const float4*)(W_a + (long)k0 * H);
#pragma unroll
    for (int s = 0; s < 8; ++s) ws[s] = wp[tid + NT * s];
  };

  auto store_chunk = [&]() {
#pragma unroll
    for (int q = 0; q < 4; ++q) {
      const int kb = lh * 16 + q * 4;
      Xl[kb + 0][lr] = xs[q].x;
      Xl[kb + 1][lr] = xs[q].y;
      Xl[kb + 2][lr] = xs[q].z;
      Xl[kb + 3][lr] = xs[q].w;
    }
    float4* wl4 = (float4*)&Wl[0][0];
#pragma unroll
    for (int s = 0; s < 8; ++s) wl4[tid + NT * s] = ws[s];
  };

  auto compute = [&]() {
#pragma unroll 8
    for (int kk = 0; kk < KC; ++kk) {
      const float4 xa = *(const float4*)&Xl[kk][rg * 8];
      const float4 xb = *(const float4*)&Xl[kk][rg * 8 + 4];
      const float4 w0 = *(const float4*)&Wl[kk][4 * cg];
      const float4 w1 = *(const float4*)&Wl[kk][4 * cg + 64];
      const float4 w2 = *(const float4*)&Wl[kk][4 * cg + 128];
      const float4 w3 = *(const float4*)&Wl[kk][4 * cg + 192];
      ROW_FMA(xa.x, 0) ROW_FMA(xa.y, 1) ROW_FMA(xa.z, 2) ROW_FMA(xa.w, 3)
      ROW_FMA(xb.x, 4) ROW_FMA(xb.y, 5) ROW_FMA(xb.z, 6) ROW_FMA(xb.w, 7)
    }
  };

  const int NC = H / KC;   // 8
  load_chunk(0);
  for (int c = 0; c < NC; ++c) {
    __syncthreads();
    store_chunk();
    __syncthreads();
    if (c + 1 < NC) load_chunk(c + 1);
    compute();
  }

  // bias + tanh in place: acc now holds g_emb fragments.
#pragma unroll
  for (int j = 0; j < 4; ++j) {
    const int col = 64 * j + 4 * cg;
    const float4 ba4 = *(const float4*)&b_a[col];
#pragma unroll
    for (int i = 0; i < 8; ++i) {
      float4 v = acc[i][j];
      v.x = fast_tanh(v.x + ba4.x);
      v.y = fast_tanh(v.y + ba4.y);
      v.z = fast_tanh(v.z + ba4.z);
      v.w = fast_tanh(v.w + ba4.w);
      acc[i][j] = v;
    }
  }

  // router logits in-register, 4 rows at a time (register budget).
#pragma unroll
  for (int hh = 0; hh < 2; ++hh) {
    float4 pl[4][4];   // [row i][ sx.lo, sx.hi, sg.lo, sg.hi ]
#pragma unroll
    for (int i = 0; i < 4; ++i)
#pragma unroll
      for (int q = 0; q < 4; ++q) pl[i][q] = make_float4(0.f, 0.f, 0.f, 0.f);

#pragma unroll
    for (int j = 0; j < 4; ++j) {
      PL_ACCUM(0, x)
      PL_ACCUM(1, y)
      PL_ACCUM(2, z)
      PL_ACCUM(3, w)
    }

    // reduce partials over the 16 cg lanes (within-wave butterfly).
#pragma unroll
    for (int i = 0; i < 4; ++i)
#pragma unroll
      for (int q = 0; q < 4; ++q) pl[i][q] = red4(pl[i][q]);

    if (cg == 0) {
#pragma unroll
      for (int i = 0; i < 4; ++i) {
        const long row = row0 + rg * 8 + hh * 4 + i;
        const float l0 = pl[i][0].x + bsx0.x;
        const float l1 = pl[i][0].y + bsx0.y;
        const float l2 = pl[i][0].z + bsx0.z;
        const float l3 = pl[i][0].w + bsx0.w;
        const float l4 = pl[i][1].x + bsx1.x;
        const float l5 = pl[i][1].y + bsx1.y;
        const float l6 = pl[i][1].z + bsx1.z;
        const float l7 = pl[i][1].w + bsx1.w;

        // softmax over 8 router logits
        const float mx = fmaxf(fmaxf(fmaxf(l0, l1), fmaxf(l2, l3)),
                               fmaxf(fmaxf(l4, l5), fmaxf(l6, l7)));
        const float e0 = __expf(l0 - mx), e1 = __expf(l1 - mx);
        const float e2 = __expf(l2 - mx), e3 = __expf(l3 - mx);
        const float e4 = __expf(l4 - mx), e5 = __expf(l5 - mx);
        const float e6 = __expf(l6 - mx), e7 = __expf(l7 - mx);
        const float inv = 1.0f / (((e0 + e1) + (e2 + e3)) + ((e4 + e5) + (e6 + e7)));
        *(float4*)&out_sm[row * EXP]     = make_float4(e0 * inv, e1 * inv, e2 * inv, e3 * inv);
        *(float4*)&out_sm[row * EXP + 4] = make_float4(e4 * inv, e5 * inv, e6 * inv, e7 * inv);

        // first-max argmax (matches jnp.argmax tie rule)
        int a = 0; float bv = l0;
        if (l1 > bv) { bv = l1; a = 1; }
        if (l2 > bv) { bv = l2; a = 2; }
        if (l3 > bv) { bv = l3; a = 3; }
        if (l4 > bv) { bv = l4; a = 4; }
        if (l5 > bv) { bv = l5; a = 5; }
        if (l6 > bv) { bv = l6; a = 6; }
        if (l7 > bv) { bv = l7; a = 7; }

        // sigmoid gate output
        const float g0 = pl[i][2].x + bsg0.x;
        const float g1 = pl[i][2].y + bsg0.y;
        const float g2 = pl[i][2].z + bsg0.z;
        const float g3 = pl[i][2].w + bsg0.w;
        const float g4 = pl[i][3].x + bsg1.x;
        const float g5 = pl[i][3].y + bsg1.y;
        const float g6 = pl[i][3].z + bsg1.z;
        const float g7 = pl[i][3].w + bsg1.w;
        *(float4*)&out_sg[row * EXP]     = make_float4(sigm(g0), sigm(g1), sigm(g2), sigm(g3));
        *(float4*)&out_sg[row * EXP + 4] = make_float4(sigm(g4), sigm(g5), sigm(g6), sigm(g7));

        // out = dot(e[row, 32a:32a+32], W_out[32a:32a+32]) + b_out
        const float* ep = e_in + row * H + a * 32;
        const float* wo = W_out + a * 32;
        float s0 = 0.f;
#pragma unroll
        for (int t = 0; t < 8; ++t) {
          const float4 ev = ((const float4*)ep)[t];
          const float4 wv = ((const float4*)wo)[t];
          s0 = fmaf(ev.x, wv.x, s0);
          s0 = fmaf(ev.y, wv.y, s0);
          s0 = fmaf(ev.z, wv.z, s0);
          s0 = fmaf(ev.w, wv.w, s0);
        }
        out0[row] = s0 + b_out0;
      }
    }
  }
}

// ---------------------------------------------------------------------------
extern "C" void kernel_launch(void* const* d_in, const int* in_sizes, int n_in,
                              void* d_out, int out_size, void* d_ws, size_t ws_size,
                              hipStream_t stream) {
  (void)n_in; (void)out_size; (void)ws_size;
  const float* s_e     = (const float*)d_in[0];
  const float* p_e     = (const float*)d_in[1];
  const float* W_fuse  = (const float*)d_in[2];
  const float* b_fuse  = (const float*)d_in[3];
  const float* W_a     = (const float*)d_in[4];
  const float* b_a     = (const float*)d_in[5];
  const float* W_smax  = (const float*)d_in[6];
  const float* b_smax  = (const float*)d_in[7];
  const float* W_smoid = (const float*)d_in[8];
  const float* b_smoid = (const float*)d_in[9];
  const float* W_out   = (const float*)d_in[10];
  const float* b_out   = (const float*)d_in[11];

  const int B = in_sizes[0] / H;          // 262144
  float* e_ws   = (float*)d_ws;           // B*H fp32 = 256 MB scratch
  float* out0   = (float*)d_out;          // [B]
  float* out_sm = out0 + (size_t)B;       // [B,8]
  float* out_sg = out_sm + (size_t)B * EXP; // [B,8]

  dim3 grid(B / BM), block(NT);
  k_fuse<<<grid, block, 0, stream>>>(s_e, p_e, W_fuse, b_fuse, e_ws);
  k_gate<<<grid, block, 0, stream>>>(e_ws, W_a, b_a, W_smax, b_smax,
                                     W_smoid, b_smoid, W_out, b_out,
                                     out0, out_sm, out_sg);
}

// Round 4
// 1265.857 us; speedup vs baseline: 1.4970x; 1.4970x over previous
//
#include <hip/hip_runtime.h>
#include <hip/hip_bf16.h>

// ---------------------------------------------------------------------------
// Round 4: split-bf16 MFMA rewrite.
//   x = hi + lo (bf16 RNE split); x*y = hi*hi + hi*lo + lo*hi (3-mult trick)
//   -> fp32-grade accuracy on MFMA pipes.
//   k_prep : split+transpose weights into __device__ bf16 planes (L2-hot).
//   k_fuse : e = relu(cat(s_e,p_e)@W_fuse+b) ; LDS-staged split A; e -> hi/lo
//            planes in ws (256 MB, proven footprint).
//   k_gate : g = tanh(e@W_a+b) fully in regs (no LDS/barriers in GEMM);
//            router logits via MFMA (16-expert padded); softmax/argmax/
//            sigmoid/out0 fused epilogue.
// MFMA 16x16x32_bf16 mapping used (guide §3, m89/m91-verified C-layout):
//   A: row=lane&15, k=8*(lane>>4)+j ; B: col=lane&15, k=8*(lane>>4)+j
//   C: col=lane&15, row=4*(lane>>4)+reg
// ---------------------------------------------------------------------------

#define H    256
#define EXP  8

using short8 = __attribute__((ext_vector_type(8))) short;
using f32x4  = __attribute__((ext_vector_type(4))) float;

// pre-split, pre-transposed weights: [n][k] layout, k contiguous
__device__ short gWF_hi[256 * 512];
__device__ short gWF_lo[256 * 512];
__device__ short gWA_hi[256 * 256];
__device__ short gWA_lo[256 * 256];
__device__ short gWR_hi[16 * 256];   // cols: e<8 -> W_smax[:,e], e>=8 -> W_smoid[:,e-8]
__device__ short gWR_lo[16 * 256];

__device__ __forceinline__ unsigned short bf16_rne(float x) {
  unsigned u = __float_as_uint(x);
  return (unsigned short)((u + 0x7fffu + ((u >> 16) & 1u)) >> 16);
}
__device__ __forceinline__ float bf16f(unsigned short h) {
  return __uint_as_float(((unsigned)h) << 16);
}
__device__ __forceinline__ float fast_tanh(float x) {
  const float u = __expf(2.0f * x);
  return 1.0f - 2.0f / (u + 1.0f);
}
__device__ __forceinline__ float sigm(float x) {
  return 1.0f / (1.0f + __expf(-x));
}

// ---------------------------------------------------------------------------
__global__ void k_prep(const float* __restrict__ Wf, const float* __restrict__ Wa,
                       const float* __restrict__ Wsx, const float* __restrict__ Wsg) {
  const int tid = blockIdx.x * 256 + threadIdx.x;   // 0 .. 200703 exact
  float x; short* ph; short* pl; int idx;
  if (tid < 131072) {                 // W_fuse [512][256] -> [256][512]
    const int n = tid >> 9, k = tid & 511;
    x = Wf[k * 256 + n]; ph = gWF_hi; pl = gWF_lo; idx = tid;
  } else if (tid < 196608) {          // W_a [256][256] -> [256][256]^T
    const int t = tid - 131072;
    const int n = t >> 8, k = t & 255;
    x = Wa[k * 256 + n]; ph = gWA_hi; pl = gWA_lo; idx = t;
  } else {                            // routers [256][8]x2 -> [16][256]
    const int t = tid - 196608;
    const int e = t >> 8, k = t & 255;
    x = (e < 8) ? Wsx[k * 8 + e] : Wsg[k * 8 + (e - 8)];
    ph = gWR_hi; pl = gWR_lo; idx = t;
  }
  const unsigned short hi = bf16_rne(x);
  const unsigned short lo = bf16_rne(x - bf16f(hi));
  ph[idx] = (short)hi; pl[idx] = (short)lo;
}

// ---------------------------------------------------------------------------
// k_fuse: BM=128, BN=256(full), NT=512 (8 waves, 2M x 4N), wave tile 64x64.
__global__ __launch_bounds__(512) void k_fuse(
    const float* __restrict__ se, const float* __restrict__ pe,
    const float* __restrict__ bfuse,
    unsigned short* __restrict__ ehi, unsigned short* __restrict__ elo) {
  __shared__ short Ah[2][128 * 32];
  __shared__ short Al[2][128 * 32];
  const int tid = threadIdx.x;
  const int lane = tid & 63, l15 = lane & 15, l4 = lane >> 4;
  const int wid = tid >> 6, wm = wid >> 2, wn = wid & 3;
  const long row0 = (long)blockIdx.x * 128;

  f32x4 acc[4][4] = {};

  const int srow = tid >> 2;          // 0..127
  const int skc = (tid & 3) * 8;      // 0,8,16,24

  float xr[8];
  auto load_regs = [&](int c) {
    const int k = c * 32 + skc;       // never straddles the 256 boundary
    const float* src = (k < 256) ? (se + (row0 + srow) * 256 + k)
                                 : (pe + (row0 + srow) * 256 + (k - 256));
    const float4 a = *(const float4*)src;
    const float4 b = *(const float4*)(src + 4);
    xr[0] = a.x; xr[1] = a.y; xr[2] = a.z; xr[3] = a.w;
    xr[4] = b.x; xr[5] = b.y; xr[6] = b.z; xr[7] = b.w;
  };
  auto write_lds = [&](int c) {
    short8 h8, l8;
#pragma unroll
    for (int j = 0; j < 8; ++j) {
      const unsigned short h = bf16_rne(xr[j]);
      h8[j] = (short)h;
      l8[j] = (short)bf16_rne(xr[j] - bf16f(h));
    }
    *(short8*)&Ah[c & 1][srow * 32 + skc] = h8;
    *(short8*)&Al[c & 1][srow * 32 + skc] = l8;
  };
  auto compute = [&](int c) {
    short8 ah[4], al[4];
    const int abase = (wm * 64 + l15) * 32 + 8 * l4;
#pragma unroll
    for (int mf = 0; mf < 4; ++mf) {
      ah[mf] = *(const short8*)&Ah[c & 1][abase + mf * 16 * 32];
      al[mf] = *(const short8*)&Al[c & 1][abase + mf * 16 * 32];
    }
    const int k0 = c * 32;
#pragma unroll
    for (int nf = 0; nf < 4; ++nf) {
      const int n = wn * 64 + nf * 16 + l15;
      const short8 bh = *(const short8*)&gWF_hi[n * 512 + k0 + 8 * l4];
      const short8 bl = *(const short8*)&gWF_lo[n * 512 + k0 + 8 * l4];
#pragma unroll
      for (int mf = 0; mf < 4; ++mf) {
        acc[mf][nf] = __builtin_amdgcn_mfma_f32_16x16x32_bf16(ah[mf], bh, acc[mf][nf], 0, 0, 0);
        acc[mf][nf] = __builtin_amdgcn_mfma_f32_16x16x32_bf16(ah[mf], bl, acc[mf][nf], 0, 0, 0);
        acc[mf][nf] = __builtin_amdgcn_mfma_f32_16x16x32_bf16(al[mf], bh, acc[mf][nf], 0, 0, 0);
      }
    }
  };

  load_regs(0);
  write_lds(0);
  for (int c = 0; c < 16; ++c) {
    __syncthreads();                  // buf[c&1] fully written
    if (c < 15) load_regs(c + 1);     // prefetch globals across compute
    compute(c);
    if (c < 15) write_lds(c + 1);     // writes buf[(c+1)&1] != read buf
  }

  // epilogue: +bias, relu, split -> hi/lo planes
#pragma unroll
  for (int nf = 0; nf < 4; ++nf) {
    const int n = wn * 64 + nf * 16 + l15;
    const float bias = bfuse[n];
#pragma unroll
    for (int mf = 0; mf < 4; ++mf) {
#pragma unroll
      for (int r = 0; r < 4; ++r) {
        const long m = row0 + wm * 64 + mf * 16 + 4 * l4 + r;
        float v = fmaxf(acc[mf][nf][r] + bias, 0.f);
        const unsigned short h = bf16_rne(v);
        ehi[m * 256 + n] = h;
        elo[m * 256 + n] = bf16_rne(v - bf16f(h));
      }
    }
  }
}

// ---------------------------------------------------------------------------
// k_gate: BM=128, BN=256, NT=512 (8 waves 2M x 4N). GEMM2 barrier-free.
#define GT_STRIDE 268   // u32; 1072 B: 16B-aligned rows, conflict-spread
__global__ __launch_bounds__(512) void k_gate(
    const unsigned short* __restrict__ ehi, const unsigned short* __restrict__ elo,
    const float* __restrict__ b_a, const float* __restrict__ bsx,
    const float* __restrict__ bsg, const float* __restrict__ Wout,
    const float* __restrict__ bout,
    float* __restrict__ out0, float* __restrict__ out_sm, float* __restrict__ out_sg) {
  __shared__ unsigned GT[64 * GT_STRIDE];   // 68608 B; praw overlays first 32 KB
  const int tid = threadIdx.x;
  const int lane = tid & 63, l15 = lane & 15, l4 = lane >> 4;
  const int wid = tid >> 6, wm = wid >> 2, wn = wid & 3;
  const long row0 = (long)blockIdx.x * 128;

  f32x4 acc[4][4] = {};

  // ---- GEMM2: g_pre = e @ W_a  (no LDS, no barriers) ----
#pragma unroll 2
  for (int ks = 0; ks < 8; ++ks) {
    const int k0 = ks * 32;
    short8 ah[4], al[4];
#pragma unroll
    for (int mf = 0; mf < 4; ++mf) {
      const long m = row0 + wm * 64 + mf * 16 + l15;
      ah[mf] = *(const short8*)(ehi + m * 256 + k0 + 8 * l4);
      al[mf] = *(const short8*)(elo + m * 256 + k0 + 8 * l4);
    }
#pragma unroll
    for (int nf = 0; nf < 4; ++nf) {
      const int n = wn * 64 + nf * 16 + l15;
      const short8 bh = *(const short8*)&gWA_hi[n * 256 + k0 + 8 * l4];
      const short8 bl = *(const short8*)&gWA_lo[n * 256 + k0 + 8 * l4];
#pragma unroll
      for (int mf = 0; mf < 4; ++mf) {
        acc[mf][nf] = __builtin_amdgcn_mfma_f32_16x16x32_bf16(ah[mf], bh, acc[mf][nf], 0, 0, 0);
        acc[mf][nf] = __builtin_amdgcn_mfma_f32_16x16x32_bf16(ah[mf], bl, acc[mf][nf], 0, 0, 0);
        acc[mf][nf] = __builtin_amdgcn_mfma_f32_16x16x32_bf16(al[mf], bh, acc[mf][nf], 0, 0, 0);
      }
    }
  }

  // ---- tanh + split-pack (hi<<16 | lo) ----
  unsigned pg[4][4][4];
#pragma unroll
  for (int nf = 0; nf < 4; ++nf) {
    const int n = wn * 64 + nf * 16 + l15;
    const float ba = b_a[n];
#pragma unroll
    for (int mf = 0; mf < 4; ++mf) {
#pragma unroll
      for (int r = 0; r < 4; ++r) {
        const float g = fast_tanh(acc[mf][nf][r] + ba);
        const unsigned short h = bf16_rne(g);
        const unsigned short lo = bf16_rne(g - bf16f(h));
        pg[mf][nf][r] = ((unsigned)h << 16) | (unsigned)lo;
      }
    }
  }

  const float bo = bout[0];

  // ---- two 64-row halves: gt-tile -> router MFMA -> reduce -> finalize ----
  for (int h = 0; h < 2; ++h) {
    if (wm == h) {
#pragma unroll
      for (int mf = 0; mf < 4; ++mf)
#pragma unroll
        for (int nf = 0; nf < 4; ++nf)
#pragma unroll
          for (int r = 0; r < 4; ++r)
            GT[(mf * 16 + 4 * l4 + r) * GT_STRIDE + wn * 64 + nf * 16 + l15] = pg[mf][nf][r];
    }
    __syncthreads();

    // router MFMA: wave wid handles features [wid*32, wid*32+32)
    f32x4 racc[4] = {};
    {
      const int k0 = wid * 32;
      const short8 rbh = *(const short8*)&gWR_hi[l15 * 256 + k0 + 8 * l4];
      const short8 rbl = *(const short8*)&gWR_lo[l15 * 256 + k0 + 8 * l4];
#pragma unroll
      for (int mf = 0; mf < 4; ++mf) {
        const int row = mf * 16 + l15;
        const uint4 u0 = *(const uint4*)&GT[row * GT_STRIDE + k0 + 8 * l4];
        const uint4 u1 = *(const uint4*)&GT[row * GT_STRIDE + k0 + 8 * l4 + 4];
        short8 gh, gl;
        gh[0] = (short)(u0.x >> 16); gl[0] = (short)(u0.x & 0xffffu);
        gh[1] = (short)(u0.y >> 16); gl[1] = (short)(u0.y & 0xffffu);
        gh[2] = (short)(u0.z >> 16); gl[2] = (short)(u0.z & 0xffffu);
        gh[3] = (short)(u0.w >> 16); gl[3] = (short)(u0.w & 0xffffu);
        gh[4] = (short)(u1.x >> 16); gl[4] = (short)(u1.x & 0xffffu);
        gh[5] = (short)(u1.y >> 16); gl[5] = (short)(u1.y & 0xffffu);
        gh[6] = (short)(u1.z >> 16); gl[6] = (short)(u1.z & 0xffffu);
        gh[7] = (short)(u1.w >> 16); gl[7] = (short)(u1.w & 0xffffu);
        racc[mf] = __builtin_amdgcn_mfma_f32_16x16x32_bf16(gh, rbh, racc[mf], 0, 0, 0);
        racc[mf] = __builtin_amdgcn_mfma_f32_16x16x32_bf16(gh, rbl, racc[mf], 0, 0, 0);
        racc[mf] = __builtin_amdgcn_mfma_f32_16x16x32_bf16(gl, rbh, racc[mf], 0, 0, 0);
      }
    }
    __syncthreads();   // gt reads done before overlay write

    // write partials: praw[wid][row 0..63][e 0..15] overlaid on GT
    float* praw = (float*)GT;
#pragma unroll
    for (int mf = 0; mf < 4; ++mf)
#pragma unroll
      for (int r = 0; r < 4; ++r)
        praw[(wid * 64 + mf * 16 + 4 * l4 + r) * 16 + l15] = racc[mf][r];
    __syncthreads();

    if (tid < 128) {
      const int r = tid >> 1, q = tid & 1;
      float s[8] = {0.f, 0.f, 0.f, 0.f, 0.f, 0.f, 0.f, 0.f};
#pragma unroll
      for (int w = 0; w < 8; ++w)
#pragma unroll
        for (int e = 0; e < 8; ++e)
          s[e] += praw[(w * 64 + r) * 16 + q * 8 + e];
      const long grow = row0 + h * 64 + r;
      if (q == 0) {
        float l[8];
#pragma unroll
        for (int e = 0; e < 8; ++e) l[e] = s[e] + bsx[e];
        float mx = l[0];
#pragma unroll
        for (int e = 1; e < 8; ++e) mx = fmaxf(mx, l[e]);
        float ex[8], sum = 0.f;
#pragma unroll
        for (int e = 0; e < 8; ++e) { ex[e] = __expf(l[e] - mx); sum += ex[e]; }
        const float inv = 1.0f / sum;
#pragma unroll
        for (int e = 0; e < 8; ++e) out_sm[grow * 8 + e] = ex[e] * inv;
        int a = 0; float bv = l[0];
#pragma unroll
        for (int e = 1; e < 8; ++e) if (l[e] > bv) { bv = l[e]; a = e; }
        // out0 = dot(e[grow, 32a:32a+32], W_out[32a:]) + b_out
        const unsigned short* eh = ehi + grow * 256 + a * 32;
        const unsigned short* el = elo + grow * 256 + a * 32;
        const float* wo = Wout + a * 32;
        float dot = 0.f;
#pragma unroll
        for (int j = 0; j < 32; ++j)
          dot = fmaf(bf16f(eh[j]) + bf16f(el[j]), wo[j], dot);
        out0[grow] = dot + bo;
      } else {
#pragma unroll
        for (int e = 0; e < 8; ++e) out_sg[grow * 8 + e] = sigm(s[e] + bsg[e]);
      }
    }
    __syncthreads();   // praw reads done before h=1 rewrites gt
  }
}

// ---------------------------------------------------------------------------
extern "C" void kernel_launch(void* const* d_in, const int* in_sizes, int n_in,
                              void* d_out, int out_size, void* d_ws, size_t ws_size,
                              hipStream_t stream) {
  (void)n_in; (void)out_size; (void)ws_size;
  const float* s_e     = (const float*)d_in[0];
  const float* p_e     = (const float*)d_in[1];
  const float* W_fuse  = (const float*)d_in[2];
  const float* b_fuse  = (const float*)d_in[3];
  const float* W_a     = (const float*)d_in[4];
  const float* b_a     = (const float*)d_in[5];
  const float* W_smax  = (const float*)d_in[6];
  const float* b_smax  = (const float*)d_in[7];
  const float* W_smoid = (const float*)d_in[8];
  const float* b_smoid = (const float*)d_in[9];
  const float* W_out   = (const float*)d_in[10];
  const float* b_out   = (const float*)d_in[11];

  const int B = in_sizes[0] / H;                       // 262144
  unsigned short* e_hi = (unsigned short*)d_ws;        // [B][256] bf16, 128 MB
  unsigned short* e_lo = e_hi + (size_t)B * H;         // [B][256] bf16, 128 MB
  float* out0   = (float*)d_out;                       // [B]
  float* out_sm = out0 + (size_t)B;                    // [B,8]
  float* out_sg = out_sm + (size_t)B * EXP;            // [B,8]

  k_prep<<<dim3(784), dim3(256), 0, stream>>>(W_fuse, W_a, W_smax, W_smoid);
  k_fuse<<<dim3(B / 128), dim3(512), 0, stream>>>(s_e, p_e, b_fuse, e_hi, e_lo);
  k_gate<<<dim3(B / 128), dim3(512), 0, stream>>>(e_hi, e_lo, b_a, b_smax, b_smoid,
                                                  W_out, b_out, out0, out_sm, out_sg);
}